// Round 23
// baseline (245.979 us; speedup 1.0000x reference)
//
#include <hip/hip_runtime.h>
#include <math.h>

typedef unsigned short u16;
typedef unsigned char u8;
typedef unsigned int u32;
typedef __attribute__((ext_vector_type(4))) float f32x4;
typedef __attribute__((ext_vector_type(8))) short s16x8;
typedef __attribute__((ext_vector_type(4))) short s16x4;
typedef __attribute__((ext_vector_type(4))) u32 u32x4;
typedef __attribute__((ext_vector_type(2))) u32 u32x2;

__device__ __forceinline__ u16 f2bf(float f) {
  unsigned u = __builtin_bit_cast(unsigned, f);
  u += 0x7fffu + ((u >> 16) & 1u);
  return (u16)(u >> 16);
}

__device__ __forceinline__ u32 cvtpk_bf16(float lo, float hi) {
  u32 r;
  asm("v_cvt_pk_bf16_f32 %0, %1, %2" : "=v"(r) : "v"(lo), "v"(hi));
  return r;
}

__device__ __forceinline__ float max3f(float a, float b, float c) {
  return fmaxf(fmaxf(a, b), c);  // fuses to v_max3_f32
}

#define GLDS16(g, l) __builtin_amdgcn_global_load_lds( \
    (const __attribute__((address_space(1))) void*)(g), \
    (__attribute__((address_space(3))) void*)(l), 16, 0, 0)

// ---------------- GEMM 2-phase, BK=64, XOR-swizzled LDS; NW waves (R22-proven) ----------
// EPI 0: bf16(acc). EPI 1: bias+ReLU. EPI 2: bias+resid -> f32. EPI 3: QKV w/ fused V^T.
template <int EPI, int BM, int NW>
__global__ __launch_bounds__(NW * 64) void gemm_bt(
    const u16* __restrict__ A, const u16* __restrict__ BT, int M, int N, int K,
    const float* __restrict__ bias, const float* __restrict__ resid,
    u16* __restrict__ outB, float* __restrict__ outF) {
  constexpr int MT = (4 * BM) / (16 * NW);   // 16-row frags per wave
  constexpr int MROWS = MT * 16;             // rows per wave
  constexpr int AC = (BM / 8) / NW;          // A 1KB-chunks per wave
  constexpr int BC = 16 / NW;                // B 1KB-chunks per wave
  __shared__ __align__(16) u16 lA[2][BM * 64];
  __shared__ __align__(16) u16 lB[2][128 * 64];
  const int tid = threadIdx.x;
  const int wave = __builtin_amdgcn_readfirstlane(tid >> 6);
  const int lane = tid & 63;
  const int l15 = lane & 15, l4 = lane >> 4;
  const int wr = wave >> 2, wc = wave & 3;   // (NW/4) M-strips x 4 N-quarters
  const int nwg = gridDim.x * gridDim.y;
  int wg = blockIdx.y * gridDim.x + blockIdx.x;
  wg = (wg & 7) * (nwg >> 3) + (wg >> 3);  // XCD swizzle (bijective: nwg%8==0)
  const int bx = wg % gridDim.x, by = wg / gridDim.x;
  const int row0 = by * BM, col0 = bx * 128;

  f32x4 acc[MT][2] = {};

  auto stage = [&](int bi, int k0) {
#pragma unroll
    for (int c = 0; c < AC; ++c) {  // A: BM rows x 128B
      const int chunk = c * NW + wave;
      const int byt = (chunk * 64 + lane) * 16;
      const int row = byt >> 7;
      const int cb = (byt & 127) ^ ((row & 7) << 4);
      GLDS16(A + (size_t)(row0 + row) * K + k0 + (cb >> 1), &lA[bi][chunk * 512]);
    }
#pragma unroll
    for (int c = 0; c < BC; ++c) {  // B: 128 rows x 128B
      const int chunk = c * NW + wave;
      const int byt = (chunk * 64 + lane) * 16;
      const int row = byt >> 7;
      const int cb = (byt & 127) ^ ((row & 7) << 4);
      GLDS16(BT + (size_t)(col0 + row) * K + k0 + (cb >> 1), &lB[bi][chunk * 512]);
    }
  };

  stage(0, 0);
  __syncthreads();
  int buf = 0;

  for (int k0 = 0; k0 < K; k0 += 64) {
    if (k0 + 64 < K) stage(buf ^ 1, k0 + 64);  // async prefetch; drained at loop-end barrier
    const char* bufA = (const char*)&lA[buf][0];
    const char* bufB = (const char*)&lB[buf][0];
#pragma unroll
    for (int s = 0; s < 2; ++s) {
      s16x8 af[MT], bfr[2];
#pragma unroll
      for (int m = 0; m < MT; ++m) {
        const int row = wr * MROWS + m * 16 + l15;
        af[m] = *(const s16x8*)(bufA + row * 128 + ((s * 64 + l4 * 16) ^ ((row & 7) << 4)));
      }
#pragma unroll
      for (int n = 0; n < 2; ++n) {
        const int row = wc * 32 + n * 16 + l15;
        bfr[n] = *(const s16x8*)(bufB + row * 128 + ((s * 64 + l4 * 16) ^ ((row & 7) << 4)));
      }
#pragma unroll
      for (int m = 0; m < MT; ++m)
#pragma unroll
        for (int n = 0; n < 2; ++n)
          acc[m][n] = __builtin_amdgcn_mfma_f32_16x16x32_bf16(af[m], bfr[n], acc[m][n], 0, 0, 0);
    }
    __syncthreads();
    buf ^= 1;
  }

  if (EPI == 3 && col0 >= 2048) {
    // V block: write transposed into vt[bh][dk][s] (vt passed via outF)
    u16* vtp = (u16*)outF;
#pragma unroll
    for (int m = 0; m < MT; ++m) {
      const int rowb = row0 + wr * MROWS + m * 16 + l4 * 4;
      const int s0 = rowb & 2047, bb = rowb >> 11;
#pragma unroll
      for (int n = 0; n < 2; ++n) {
        const int cv = col0 + wc * 32 + n * 16 + l15 - 2048;
        const int hv = cv >> 6, dk = cv & 63;
        const u32 lo = cvtpk_bf16(acc[m][n][0], acc[m][n][1]);
        const u32 hi = cvtpk_bf16(acc[m][n][2], acc[m][n][3]);
        u16* p = vtp + ((size_t)(bb * 16 + hv) * 64 + dk) * 2048 + s0;
        *(u32x2*)p = u32x2{lo, hi};
      }
    }
    return;
  }

#pragma unroll
  for (int m = 0; m < MT; ++m) {
    const int rowb = row0 + wr * MROWS + m * 16 + l4 * 4;
#pragma unroll
    for (int n = 0; n < 2; ++n) {
      const int col = col0 + wc * 32 + n * 16 + l15;
#pragma unroll
      for (int j = 0; j < 4; ++j) {
        const int r = rowb + j;
        float v = acc[m][n][j];
        if (EPI == 0 || EPI == 3) {
          outB[(size_t)r * N + col] = f2bf(v);
        } else if (EPI == 1) {
          v += bias[col];
          outB[(size_t)r * N + col] = f2bf(v > 0.0f ? v : 0.0f);
        } else {
          v += bias[col] + resid[(size_t)r * N + col];
          outF[(size_t)r * N + col] = v;
        }
      }
    }
  }
}

// ---------------- ALL prep work in ONE flat dispatch (R20-proven) ----------------
__global__ __launch_bounds__(256) void prep_all(
    const float* __restrict__ Wq, const float* __restrict__ Wk,
    const float* __restrict__ Wv, const float* __restrict__ Wo,
    const float* __restrict__ W1, const float* __restrict__ W2,
    const float* __restrict__ x, const u8* __restrict__ mask,
    u16* __restrict__ wqkvT, u16* __restrict__ woT,
    u16* __restrict__ w1T, u16* __restrict__ w2T,
    u16* __restrict__ xb, u8* __restrict__ msum) {
  __shared__ float t[32][33];
  __shared__ int any_flag;
  const int id = blockIdx.x;
  const int tid = threadIdx.x;

  if (id < 12288) {  // transposes
    const float* in;
    u16* out;
    int R, C, bx, by;
    if (id < 4096) {
      const int z = id >> 10, r = id & 1023;
      in = (z == 0) ? Wq : (z == 1) ? Wk : (z == 2) ? Wv : Wo;
      out = (z < 3) ? (wqkvT + (size_t)z * 1024 * 1024) : woT;
      R = 1024; C = 1024; bx = r & 31; by = r >> 5;
    } else if (id < 8192) {
      const int r = id - 4096;
      in = W1; out = w1T; R = 1024; C = 4096; bx = r & 127; by = r >> 7;
    } else {
      const int r = id - 8192;
      in = W2; out = w2T; R = 4096; C = 1024; bx = r & 31; by = r >> 5;
    }
    const int c0 = bx * 32, r0 = by * 32;
    const int tx = tid & 31, ty = tid >> 5;
#pragma unroll
    for (int i = 0; i < 4; ++i)
      t[ty + i * 8][tx] = in[(size_t)(r0 + ty + i * 8) * C + c0 + tx];
    __syncthreads();
#pragma unroll
    for (int i = 0; i < 4; ++i)
      out[(size_t)(c0 + ty + i * 8) * R + r0 + tx] = f2bf(t[tx][ty + i * 8]);
  } else if (id < 16384) {  // x f32 -> bf16 (4 elems/thread)
    const int i = (id - 12288) * 256 + tid;
    f32x4 v = *(const f32x4*)&x[(size_t)i * 4];
    s16x4 o;
#pragma unroll
    for (int j = 0; j < 4; ++j) o[j] = (short)f2bf(v[j]);
    *(s16x4*)&xb[(size_t)i * 4] = o;
  } else {  // mask tile summary
    const int r = id - 16384;
    const int kt = r & 31, qt = (r >> 5) & 31, b = r >> 10;
    if (tid == 0) any_flag = 0;
    __syncthreads();
    const u8* base = mask + ((size_t)(b * 2048 + qt * 64 + (tid >> 2))) * 2048 + kt * 64 + (tid & 3) * 16;
    const u32x4 v = *(const u32x4*)base;
    if (v[0] | v[1] | v[2] | v[3]) any_flag = 1;
    __syncthreads();
    if (tid == 0) msum[((size_t)b * 32 + qt) * 32 + kt] = (u8)any_flag;
  }
}

// ---------------- LayerNorm over D=1024 ----------------
template <int WB>
__global__ __launch_bounds__(256) void layernorm_k(
    const float* __restrict__ in, const float* __restrict__ gm, const float* __restrict__ bt,
    float* __restrict__ outF, u16* __restrict__ outB) {
  const int row = blockIdx.x;
  const int t = threadIdx.x;
  const float* xr = in + (size_t)row * 1024;
  f32x4 v = *(const f32x4*)&xr[t * 4];
  float s = v[0] + v[1] + v[2] + v[3];
  float s2 = v[0] * v[0] + v[1] * v[1] + v[2] * v[2] + v[3] * v[3];
#pragma unroll
  for (int o = 32; o; o >>= 1) {
    s += __shfl_down(s, o);
    s2 += __shfl_down(s2, o);
  }
  __shared__ float red[8];
  const int lane = t & 63, wv = t >> 6;
  if (lane == 0) { red[wv] = s; red[4 + wv] = s2; }
  __syncthreads();
  s = red[0] + red[1] + red[2] + red[3];
  s2 = red[4] + red[5] + red[6] + red[7];
  const float mu = s * (1.0f / 1024.0f);
  const float var = fmaxf(s2 * (1.0f / 1024.0f) - mu * mu, 0.0f);
  const float rs = rsqrtf(var + 1e-5f);
  f32x4 g4 = *(const f32x4*)&gm[t * 4];
  f32x4 b4 = *(const f32x4*)&bt[t * 4];
  f32x4 ov;
#pragma unroll
  for (int j = 0; j < 4; ++j) ov[j] = (v[j] - mu) * rs * g4[j] + b4[j];
  *(f32x4*)&outF[(size_t)row * 1024 + t * 4] = ov;
  if (WB) {
    s16x4 ob;
#pragma unroll
    for (int j = 0; j < 4; ++j) ob[j] = (short)f2bf(ov[j]);
    *(s16x4*)&outB[(size_t)row * 1024 + t * 4] = ob;
  }
}

// ---------------- flash attention: R17-exact body (87.5us best-measured) ----------------
// 512 blocks x 512 threads; wave = one frozen 16-row q-group; 8 waves share one
// staged KVBLK=64 tile (32KB LDS dbuf); one GLDS16 per matrix per wave per tile.
__global__ __launch_bounds__(512) void attn_k(
    const u16* __restrict__ QKV, const u16* __restrict__ VT,
    const u8* __restrict__ mask, const u8* __restrict__ msum, u16* __restrict__ out) {
  const int S = 2048, QSTR = 3072, Dm = 1024;
  const int wgid = blockIdx.x;  // 0..511
  const int xcd = wgid & 7, slot = wgid >> 3;  // slot 0..63
  const int bh = xcd * 4 + (slot >> 4);        // 4 bh per XCD -> KV L2-resident
  const int qt = slot & 15;                    // 16 q-tiles of 128 rows
  const int b = bh >> 4, h = bh & 15;
  const int wave = threadIdx.x >> 6, lane = threadIdx.x & 63;
  const int l15 = lane & 15, l4 = lane >> 4;
  const int q0 = qt * 128 + wave * 16;
  const float CE = 0.125f * 1.44269504f;  // 1/sqrt(64) * log2(e)

  __shared__ __align__(16) u16 lK[2][4096];  // [buf][64 x 64], XOR-swizzled
  __shared__ __align__(16) u16 lV[2][4096];

  const size_t qoff = (size_t)(b * S + q0 + l15) * QSTR + h * 64;
  const s16x8 qa0 = *(const s16x8*)&QKV[qoff + l4 * 8];
  const s16x8 qa1 = *(const s16x8*)&QKV[qoff + 32 + l4 * 8];

  f32x4 o[4] = {};
  float mr = -1e30f, lr = 0.0f;
  const u8* mb = mask + (size_t)b * S * S;
  const u8* msb = msum + (size_t)(b * 32 + qt * 2 + (wave >> 2)) * 32;
  const u16* vbase = VT + (size_t)bh * 64 * S;
  const int bS = b * S;

  // 8 waves each stage 1KB of K and V per kv-64 tile (one GLDS16 per matrix).
  auto stage = [&](int bi, int kvv) {
    const int byt = (wave * 64 + lane) * 16;  // 0..8191
    const int row = byt >> 7;
    const int cb = (byt & 127) ^ ((row & 7) << 4);
    GLDS16(QKV + (size_t)(bS + kvv + row) * QSTR + 1024 + h * 64 + (cb >> 1),
           &lK[bi][wave * 512]);
    GLDS16(vbase + (size_t)row * S + kvv + (cb >> 1),
           &lV[bi][wave * 512]);
  };

  auto body = [&](int bi, int kvv) {
    if (kvv + 64 < S) stage(bi ^ 1, kvv + 64);
    const char* kbuf = (const char*)&lK[bi][0];
    const char* vbuf = (const char*)&lV[bi][0];

    f32x4 sc[4];
    __builtin_amdgcn_s_setprio(1);
#pragma unroll
    for (int t = 0; t < 4; ++t) {
      const int row = t * 16 + l15;
      const int sw = (row & 7) << 4;
      const s16x8 kf0 = *(const s16x8*)(kbuf + row * 128 + ((l4 * 16) ^ sw));
      const s16x8 kf1 = *(const s16x8*)(kbuf + row * 128 + ((64 + l4 * 16) ^ sw));
      f32x4 z = {};
      z = __builtin_amdgcn_mfma_f32_16x16x32_bf16(kf0, qa0, z, 0, 0, 0);
      z = __builtin_amdgcn_mfma_f32_16x16x32_bf16(kf1, qa1, z, 0, 0, 0);
      sc[t] = z;
    }
    __builtin_amdgcn_s_setprio(0);
    if (msb[kvv >> 6]) {
#pragma unroll
      for (int t = 0; t < 4; ++t) {
        const uchar4 m4 = *(const uchar4*)&mb[(size_t)(q0 + l15) * S + kvv + t * 16 + l4 * 4];
        if (m4.x) sc[t][0] = -1e30f;
        if (m4.y) sc[t][1] = -1e30f;
        if (m4.z) sc[t][2] = -1e30f;
        if (m4.w) sc[t][3] = -1e30f;
      }
    }
    float pm = max3f(sc[0][0], sc[0][1], sc[0][2]);
    pm = max3f(pm, sc[0][3], sc[1][0]);
    pm = max3f(pm, sc[1][1], sc[1][2]);
    pm = max3f(pm, sc[1][3], sc[2][0]);
    pm = max3f(pm, sc[2][1], sc[2][2]);
    pm = max3f(pm, sc[2][3], sc[3][0]);
    pm = max3f(pm, sc[3][1], sc[3][2]);
    pm = fmaxf(pm, sc[3][3]);
    pm = fmaxf(pm, __shfl_xor(pm, 16));
    pm = fmaxf(pm, __shfl_xor(pm, 32));
    if (!__all(pm <= mr + 44.0f)) {  // 44 raw = 8 exp2-units
      const float mn = fmaxf(mr, pm);
      const float al = exp2f((mr - mn) * CE);
      mr = mn;
      lr *= al;
#pragma unroll
      for (int n = 0; n < 4; ++n)
#pragma unroll
        for (int j = 0; j < 4; ++j) o[n][j] *= al;
    }
    const float mrc = mr * CE;
    float rsum = 0.0f;
#pragma unroll
    for (int t = 0; t < 4; ++t)
#pragma unroll
      for (int j = 0; j < 4; ++j) {
        const float p = exp2f(fmaf(sc[t][j], CE, -mrc));
        sc[t][j] = p;
        rsum += p;
      }
    rsum += __shfl_xor(rsum, 16);
    rsum += __shfl_xor(rsum, 32);
    lr += rsum;
    s16x4 pb[4];
#pragma unroll
    for (int t = 0; t < 4; ++t) {
      const u32 lo = cvtpk_bf16(sc[t][0], sc[t][1]);
      const u32 hi = cvtpk_bf16(sc[t][2], sc[t][3]);
      pb[t] = __builtin_bit_cast(s16x4, u32x2{lo, hi});
    }
    __builtin_amdgcn_s_setprio(1);
#pragma unroll
    for (int n = 0; n < 4; ++n) {
      const int row = n * 16 + l15;
      const int sw = (row & 7) << 4;
#pragma unroll
      for (int t = 0; t < 4; ++t) {
        const s16x4 va = *(const s16x4*)(vbuf + row * 128 + ((t * 32 + l4 * 8) ^ sw));
        o[n] = __builtin_amdgcn_mfma_f32_16x16x16bf16_1k(va, pb[t], o[n], 0, 0, 0);
      }
    }
    __builtin_amdgcn_s_setprio(0);
    __syncthreads();
  };

  stage(0, 0);
  __syncthreads();
  for (int kv = 0; kv < S; kv += 128) {
    body(0, kv);
    body(1, kv + 64);
  }
  const float inv = lr > 0.0f ? 1.0f / lr : 0.0f;
  const size_t obase = (size_t)(b * S + q0 + l15) * Dm + h * 64;
#pragma unroll
  for (int n = 0; n < 4; ++n) {
    const u32 lo = cvtpk_bf16(o[n][0] * inv, o[n][1] * inv);
    const u32 hi = cvtpk_bf16(o[n][2] * inv, o[n][3] * inv);
    *(u32x2*)&out[obase + n * 16 + l4 * 4] = u32x2{lo, hi};
  }
}

extern "C" void kernel_launch(void* const* d_in, const int* in_sizes, int n_in,
                              void* d_out, int out_size, void* d_ws, size_t ws_size,
                              hipStream_t stream) {
  (void)in_sizes; (void)n_in; (void)out_size; (void)ws_size;
  const float* x = (const float*)d_in[0];
  const u8* mask = (const u8*)d_in[1];
  const float* Wq = (const float*)d_in[2];
  const float* Wk = (const float*)d_in[3];
  const float* Wv = (const float*)d_in[4];
  const float* Wo = (const float*)d_in[5];
  const float* bo = (const float*)d_in[6];
  const float* W1 = (const float*)d_in[7];
  const float* b1 = (const float*)d_in[8];
  const float* W2 = (const float*)d_in[9];
  const float* b2 = (const float*)d_in[10];
  const float* g1 = (const float*)d_in[11];
  const float* be1 = (const float*)d_in[12];
  const float* g2 = (const float*)d_in[13];
  const float* be2 = (const float*)d_in[14];
  float* outp = (float*)d_out;

  const int B = 2, S = 2048, D = 1024, FF = 4096;
  const int M = B * S;  // 4096
  char* w = (char*)d_ws;
  const size_t MB = 1024 * 1024;
  u16* wqkvT = (u16*)(w + 0 * MB);    // [3072,1024] bf16   [0,6)
  u16* woT = (u16*)(w + 6 * MB);      // [1024,1024]        [6,8)
  u16* w1T = (u16*)(w + 8 * MB);      // [4096,1024]        [8,16)
  u16* w2T = (u16*)(w + 16 * MB);     // [1024,4096]        [16,24)
  u16* xb  = (u16*)(w + 24 * MB);     // [4096,1024]        [24,32)
  u16* qkv = (u16*)(w + 32 * MB);     // [4096,3072]        [32,56)
  u16* vt  = (u16*)(w + 56 * MB);     // [B*H,64,S]         [56,64)
  float* x0f = (float*)(w + 64 * MB); // [4096,1024] f32    [64,80)
  float* x1f = (float*)(w + 80 * MB); //                    [80,96)
  u16* x1b = (u16*)(w + 96 * MB);     // [4096,1024] bf16   [96,104)
  u8* msum = (u8*)(w + 64 * MB);      // 2 KB, dead before x0f is written
  u16* attn_o = xb;                   // xb dead after QKV gemm
  u16* ff1 = (u16*)(w + 32 * MB);     // [4096,4096] bf16, reuses qkv+vt [32,64)
  float* y0f = x0f;

  // ALL prep (6 weight transposes + x cvt + mask summary) in ONE dispatch
  prep_all<<<dim3(18432), 256, 0, stream>>>(Wq, Wk, Wv, Wo, W1, W2, x, mask,
                                            wqkvT, woT, w1T, w2T, xb, msum);

  // fused QKV projection; V third written directly transposed into vt (EPI=3); 16 waves
  gemm_bt<3, 128, 16><<<dim3(3 * D / 128, M / 128), 1024, 0, stream>>>(xb, wqkvT, M, 3 * D, D, nullptr, nullptr, qkv, (float*)vt);

  // attention: 512 blocks x 8 waves, KVBLK=64 (R17-exact, 87.5us best-measured)
  attn_k<<<dim3(512), 512, 0, stream>>>(qkv, vt, mask, msum, attn_o);

  // Wo projection + bias + residual(x) -- BM=64, 8 waves (3 blocks/CU)
  gemm_bt<2, 64, 8><<<dim3(D / 128, M / 64), 512, 0, stream>>>(attn_o, woT, M, D, D, bo, x, nullptr, x0f);
  layernorm_k<1><<<dim3(M), 256, 0, stream>>>(x0f, g1, be1, x1f, x1b);
  // FFN1 -- 16 waves
  gemm_bt<1, 128, 16><<<dim3(FF / 128, M / 128), 1024, 0, stream>>>(x1b, w1T, M, FF, D, b1, nullptr, ff1, nullptr);
  gemm_bt<2, 64, 8><<<dim3(D / 128, M / 64), 512, 0, stream>>>(ff1, w2T, M, D, FF, b2, x1f, nullptr, y0f);
  layernorm_k<0><<<dim3(M), 256, 0, stream>>>(y0f, g2, be2, outp, nullptr);
}

// Round 24
// 240.821 us; speedup vs baseline: 1.0214x; 1.0214x over previous
//
#include <hip/hip_runtime.h>
#include <math.h>

typedef unsigned short u16;
typedef unsigned char u8;
typedef unsigned int u32;
typedef __attribute__((ext_vector_type(4))) float f32x4;
typedef __attribute__((ext_vector_type(8))) short s16x8;
typedef __attribute__((ext_vector_type(4))) short s16x4;
typedef __attribute__((ext_vector_type(4))) u32 u32x4;
typedef __attribute__((ext_vector_type(2))) u32 u32x2;

__device__ __forceinline__ u16 f2bf(float f) {
  unsigned u = __builtin_bit_cast(unsigned, f);
  u += 0x7fffu + ((u >> 16) & 1u);
  return (u16)(u >> 16);
}

__device__ __forceinline__ u32 cvtpk_bf16(float lo, float hi) {
  u32 r;
  asm("v_cvt_pk_bf16_f32 %0, %1, %2" : "=v"(r) : "v"(lo), "v"(hi));
  return r;
}

__device__ __forceinline__ float max3f(float a, float b, float c) {
  return fmaxf(fmaxf(a, b), c);  // fuses to v_max3_f32
}

#define GLDS16(g, l) __builtin_amdgcn_global_load_lds( \
    (const __attribute__((address_space(1))) void*)(g), \
    (__attribute__((address_space(3))) void*)(l), 16, 0, 0)

// ---------------- GEMM 2-phase, BK=64, XOR-swizzled LDS; NW waves (R22-proven best) ------
// EPI 0: bf16(acc). EPI 1: bias+ReLU. EPI 2: bias+resid -> f32. EPI 3: QKV w/ fused V^T.
template <int EPI, int BM, int NW>
__global__ __launch_bounds__(NW * 64) void gemm_bt(
    const u16* __restrict__ A, const u16* __restrict__ BT, int M, int N, int K,
    const float* __restrict__ bias, const float* __restrict__ resid,
    u16* __restrict__ outB, float* __restrict__ outF) {
  constexpr int MT = (4 * BM) / (16 * NW);   // 16-row frags per wave
  constexpr int MROWS = MT * 16;             // rows per wave
  constexpr int AC = (BM / 8) / NW;          // A 1KB-chunks per wave
  constexpr int BC = 16 / NW;                // B 1KB-chunks per wave
  __shared__ __align__(16) u16 lA[2][BM * 64];
  __shared__ __align__(16) u16 lB[2][128 * 64];
  const int tid = threadIdx.x;
  const int wave = __builtin_amdgcn_readfirstlane(tid >> 6);
  const int lane = tid & 63;
  const int l15 = lane & 15, l4 = lane >> 4;
  const int wr = wave >> 2, wc = wave & 3;   // (NW/4) M-strips x 4 N-quarters
  const int nwg = gridDim.x * gridDim.y;
  int wg = blockIdx.y * gridDim.x + blockIdx.x;
  wg = (wg & 7) * (nwg >> 3) + (wg >> 3);  // XCD swizzle (bijective: nwg%8==0)
  const int bx = wg % gridDim.x, by = wg / gridDim.x;
  const int row0 = by * BM, col0 = bx * 128;

  f32x4 acc[MT][2] = {};

  auto stage = [&](int bi, int k0) {
#pragma unroll
    for (int c = 0; c < AC; ++c) {  // A: BM rows x 128B
      const int chunk = c * NW + wave;
      const int byt = (chunk * 64 + lane) * 16;
      const int row = byt >> 7;
      const int cb = (byt & 127) ^ ((row & 7) << 4);
      GLDS16(A + (size_t)(row0 + row) * K + k0 + (cb >> 1), &lA[bi][chunk * 512]);
    }
#pragma unroll
    for (int c = 0; c < BC; ++c) {  // B: 128 rows x 128B
      const int chunk = c * NW + wave;
      const int byt = (chunk * 64 + lane) * 16;
      const int row = byt >> 7;
      const int cb = (byt & 127) ^ ((row & 7) << 4);
      GLDS16(BT + (size_t)(col0 + row) * K + k0 + (cb >> 1), &lB[bi][chunk * 512]);
    }
  };

  stage(0, 0);
  __syncthreads();
  int buf = 0;

  for (int k0 = 0; k0 < K; k0 += 64) {
    if (k0 + 64 < K) stage(buf ^ 1, k0 + 64);  // async prefetch; drained at loop-end barrier
    const char* bufA = (const char*)&lA[buf][0];
    const char* bufB = (const char*)&lB[buf][0];
#pragma unroll
    for (int s = 0; s < 2; ++s) {
      s16x8 af[MT], bfr[2];
#pragma unroll
      for (int m = 0; m < MT; ++m) {
        const int row = wr * MROWS + m * 16 + l15;
        af[m] = *(const s16x8*)(bufA + row * 128 + ((s * 64 + l4 * 16) ^ ((row & 7) << 4)));
      }
#pragma unroll
      for (int n = 0; n < 2; ++n) {
        const int row = wc * 32 + n * 16 + l15;
        bfr[n] = *(const s16x8*)(bufB + row * 128 + ((s * 64 + l4 * 16) ^ ((row & 7) << 4)));
      }
#pragma unroll
      for (int m = 0; m < MT; ++m)
#pragma unroll
        for (int n = 0; n < 2; ++n)
          acc[m][n] = __builtin_amdgcn_mfma_f32_16x16x32_bf16(af[m], bfr[n], acc[m][n], 0, 0, 0);
    }
    __syncthreads();
    buf ^= 1;
  }

  if (EPI == 3 && col0 >= 2048) {
    // V block: write transposed into vt[bh][dk][s] (vt passed via outF)
    u16* vtp = (u16*)outF;
#pragma unroll
    for (int m = 0; m < MT; ++m) {
      const int rowb = row0 + wr * MROWS + m * 16 + l4 * 4;
      const int s0 = rowb & 2047, bb = rowb >> 11;
#pragma unroll
      for (int n = 0; n < 2; ++n) {
        const int cv = col0 + wc * 32 + n * 16 + l15 - 2048;
        const int hv = cv >> 6, dk = cv & 63;
        const u32 lo = cvtpk_bf16(acc[m][n][0], acc[m][n][1]);
        const u32 hi = cvtpk_bf16(acc[m][n][2], acc[m][n][3]);
        u16* p = vtp + ((size_t)(bb * 16 + hv) * 64 + dk) * 2048 + s0;
        *(u32x2*)p = u32x2{lo, hi};
      }
    }
    return;
  }

#pragma unroll
  for (int m = 0; m < MT; ++m) {
    const int rowb = row0 + wr * MROWS + m * 16 + l4 * 4;
#pragma unroll
    for (int n = 0; n < 2; ++n) {
      const int col = col0 + wc * 32 + n * 16 + l15;
#pragma unroll
      for (int j = 0; j < 4; ++j) {
        const int r = rowb + j;
        float v = acc[m][n][j];
        if (EPI == 0 || EPI == 3) {
          outB[(size_t)r * N + col] = f2bf(v);
        } else if (EPI == 1) {
          v += bias[col];
          outB[(size_t)r * N + col] = f2bf(v > 0.0f ? v : 0.0f);
        } else {
          v += bias[col] + resid[(size_t)r * N + col];
          outF[(size_t)r * N + col] = v;
        }
      }
    }
  }
}

// ---------------- ALL prep work in ONE flat dispatch (R20-proven) ----------------
__global__ __launch_bounds__(256) void prep_all(
    const float* __restrict__ Wq, const float* __restrict__ Wk,
    const float* __restrict__ Wv, const float* __restrict__ Wo,
    const float* __restrict__ W1, const float* __restrict__ W2,
    const float* __restrict__ x, const u8* __restrict__ mask,
    u16* __restrict__ wqkvT, u16* __restrict__ woT,
    u16* __restrict__ w1T, u16* __restrict__ w2T,
    u16* __restrict__ xb, u8* __restrict__ msum) {
  __shared__ float t[32][33];
  __shared__ int any_flag;
  const int id = blockIdx.x;
  const int tid = threadIdx.x;

  if (id < 12288) {  // transposes
    const float* in;
    u16* out;
    int R, C, bx, by;
    if (id < 4096) {
      const int z = id >> 10, r = id & 1023;
      in = (z == 0) ? Wq : (z == 1) ? Wk : (z == 2) ? Wv : Wo;
      out = (z < 3) ? (wqkvT + (size_t)z * 1024 * 1024) : woT;
      R = 1024; C = 1024; bx = r & 31; by = r >> 5;
    } else if (id < 8192) {
      const int r = id - 4096;
      in = W1; out = w1T; R = 1024; C = 4096; bx = r & 127; by = r >> 7;
    } else {
      const int r = id - 8192;
      in = W2; out = w2T; R = 4096; C = 1024; bx = r & 31; by = r >> 5;
    }
    const int c0 = bx * 32, r0 = by * 32;
    const int tx = tid & 31, ty = tid >> 5;
#pragma unroll
    for (int i = 0; i < 4; ++i)
      t[ty + i * 8][tx] = in[(size_t)(r0 + ty + i * 8) * C + c0 + tx];
    __syncthreads();
#pragma unroll
    for (int i = 0; i < 4; ++i)
      out[(size_t)(c0 + ty + i * 8) * R + r0 + tx] = f2bf(t[tx][ty + i * 8]);
  } else if (id < 16384) {  // x f32 -> bf16 (4 elems/thread)
    const int i = (id - 12288) * 256 + tid;
    f32x4 v = *(const f32x4*)&x[(size_t)i * 4];
    s16x4 o;
#pragma unroll
    for (int j = 0; j < 4; ++j) o[j] = (short)f2bf(v[j]);
    *(s16x4*)&xb[(size_t)i * 4] = o;
  } else {  // mask tile summary
    const int r = id - 16384;
    const int kt = r & 31, qt = (r >> 5) & 31, b = r >> 10;
    if (tid == 0) any_flag = 0;
    __syncthreads();
    const u8* base = mask + ((size_t)(b * 2048 + qt * 64 + (tid >> 2))) * 2048 + kt * 64 + (tid & 3) * 16;
    const u32x4 v = *(const u32x4*)base;
    if (v[0] | v[1] | v[2] | v[3]) any_flag = 1;
    __syncthreads();
    if (tid == 0) msum[((size_t)b * 32 + qt) * 32 + kt] = (u8)any_flag;
  }
}

// ---------------- LayerNorm over D=1024 ----------------
template <int WB>
__global__ __launch_bounds__(256) void layernorm_k(
    const float* __restrict__ in, const float* __restrict__ gm, const float* __restrict__ bt,
    float* __restrict__ outF, u16* __restrict__ outB) {
  const int row = blockIdx.x;
  const int t = threadIdx.x;
  const float* xr = in + (size_t)row * 1024;
  f32x4 v = *(const f32x4*)&xr[t * 4];
  float s = v[0] + v[1] + v[2] + v[3];
  float s2 = v[0] * v[0] + v[1] * v[1] + v[2] * v[2] + v[3] * v[3];
#pragma unroll
  for (int o = 32; o; o >>= 1) {
    s += __shfl_down(s, o);
    s2 += __shfl_down(s2, o);
  }
  __shared__ float red[8];
  const int lane = t & 63, wv = t >> 6;
  if (lane == 0) { red[wv] = s; red[4 + wv] = s2; }
  __syncthreads();
  s = red[0] + red[1] + red[2] + red[3];
  s2 = red[4] + red[5] + red[6] + red[7];
  const float mu = s * (1.0f / 1024.0f);
  const float var = fmaxf(s2 * (1.0f / 1024.0f) - mu * mu, 0.0f);
  const float rs = rsqrtf(var + 1e-5f);
  f32x4 g4 = *(const f32x4*)&gm[t * 4];
  f32x4 b4 = *(const f32x4*)&bt[t * 4];
  f32x4 ov;
#pragma unroll
  for (int j = 0; j < 4; ++j) ov[j] = (v[j] - mu) * rs * g4[j] + b4[j];
  *(f32x4*)&outF[(size_t)row * 1024 + t * 4] = ov;
  if (WB) {
    s16x4 ob;
#pragma unroll
    for (int j = 0; j < 4; ++j) ob[j] = (short)f2bf(ov[j]);
    *(s16x4*)&outB[(size_t)row * 1024 + t * 4] = ob;
  }
}

// ---------------- flash attention: 8-wave shared staging, KVBLK=128 (R22-proven best) ----
__global__ __launch_bounds__(512) void attn_k(
    const u16* __restrict__ QKV, const u16* __restrict__ VT,
    const u8* __restrict__ mask, const u8* __restrict__ msum, u16* __restrict__ out) {
  const int S = 2048, QSTR = 3072, Dm = 1024;
  const int wgid = blockIdx.x;  // 0..511
  const int xcd = wgid & 7, slot = wgid >> 3;  // slot 0..63
  const int bh = xcd * 4 + (slot >> 4);        // 4 bh per XCD -> KV L2-resident
  const int qt = slot & 15;                    // 16 q-tiles of 128 rows
  const int b = bh >> 4, h = bh & 15;
  const int wave = threadIdx.x >> 6, lane = threadIdx.x & 63;
  const int l15 = lane & 15, l4 = lane >> 4;
  const int q0 = qt * 128 + wave * 16;
  const float CE = 0.125f * 1.44269504f;  // 1/sqrt(64) * log2(e)

  __shared__ __align__(16) u16 lK[2][8192];  // [buf][128 kv x 64 dk], 128B rows, XOR-swz
  __shared__ __align__(16) u16 lV[2][8192];  // [buf][64 dk x 128 kv], 256B rows, XOR-swz

  const size_t qoff = (size_t)(b * S + q0 + l15) * QSTR + h * 64;
  const s16x8 qa0 = *(const s16x8*)&QKV[qoff + l4 * 8];
  const s16x8 qa1 = *(const s16x8*)&QKV[qoff + 32 + l4 * 8];

  f32x4 o[4] = {};
  float mr = -1e30f, lr = 0.0f;
  const u8* mb = mask + (size_t)b * S * S;
  const u8* msb = msum + (size_t)(b * 32 + qt * 2 + (wave >> 2)) * 32;
  const u16* vbase = VT + (size_t)bh * 64 * S;
  const int bS = b * S;

  auto stage = [&](int bi, int kvv) {
#pragma unroll
    for (int c = 0; c < 2; ++c) {
      const int byt = ((c * 8 + wave) * 64 + lane) * 16;  // 0..16383
      const int krow = byt >> 7;                           // K: 128B rows
      const int kcb = (byt & 127) ^ ((krow & 7) << 4);
      GLDS16(QKV + (size_t)(bS + kvv + krow) * QSTR + 1024 + h * 64 + (kcb >> 1),
             &lK[bi][(c * 8 + wave) * 512]);
      const int vrow = byt >> 8;                           // V: 256B rows
      const int vcb = (byt & 255) ^ ((vrow & 7) << 4);
      GLDS16(vbase + (size_t)vrow * S + kvv + (vcb >> 1),
             &lV[bi][(c * 8 + wave) * 512]);
    }
  };

  auto body = [&](int bi, int kvv) {
    if (kvv + 128 < S) stage(bi ^ 1, kvv + 128);
    const char* kbuf = (const char*)&lK[bi][0];
    const char* vbuf = (const char*)&lV[bi][0];
#pragma unroll
    for (int hf = 0; hf < 2; ++hf) {
      const int kvh = kvv + hf * 64;
      f32x4 sc[4];
      __builtin_amdgcn_s_setprio(1);
#pragma unroll
      for (int t = 0; t < 4; ++t) {
        const int row = hf * 64 + t * 16 + l15;
        const int sw = (row & 7) << 4;
        const s16x8 kf0 = *(const s16x8*)(kbuf + row * 128 + ((l4 * 16) ^ sw));
        const s16x8 kf1 = *(const s16x8*)(kbuf + row * 128 + ((64 + l4 * 16) ^ sw));
        f32x4 z = {};
        z = __builtin_amdgcn_mfma_f32_16x16x32_bf16(kf0, qa0, z, 0, 0, 0);
        z = __builtin_amdgcn_mfma_f32_16x16x32_bf16(kf1, qa1, z, 0, 0, 0);
        sc[t] = z;
      }
      __builtin_amdgcn_s_setprio(0);
      if (msb[kvh >> 6]) {
#pragma unroll
        for (int t = 0; t < 4; ++t) {
          const uchar4 m4 = *(const uchar4*)&mb[(size_t)(q0 + l15) * S + kvh + t * 16 + l4 * 4];
          if (m4.x) sc[t][0] = -1e30f;
          if (m4.y) sc[t][1] = -1e30f;
          if (m4.z) sc[t][2] = -1e30f;
          if (m4.w) sc[t][3] = -1e30f;
        }
      }
      float pm = max3f(sc[0][0], sc[0][1], sc[0][2]);
      pm = max3f(pm, sc[0][3], sc[1][0]);
      pm = max3f(pm, sc[1][1], sc[1][2]);
      pm = max3f(pm, sc[1][3], sc[2][0]);
      pm = max3f(pm, sc[2][1], sc[2][2]);
      pm = max3f(pm, sc[2][3], sc[3][0]);
      pm = max3f(pm, sc[3][1], sc[3][2]);
      pm = fmaxf(pm, sc[3][3]);
      pm = fmaxf(pm, __shfl_xor(pm, 16));
      pm = fmaxf(pm, __shfl_xor(pm, 32));
      if (!__all(pm <= mr + 44.0f)) {  // 44 raw = 8 exp2-units
        const float mn = fmaxf(mr, pm);
        const float al = exp2f((mr - mn) * CE);
        mr = mn;
        lr *= al;
#pragma unroll
        for (int n = 0; n < 4; ++n)
#pragma unroll
          for (int j = 0; j < 4; ++j) o[n][j] *= al;
      }
      const float mrc = mr * CE;
      float rsum = 0.0f;
#pragma unroll
      for (int t = 0; t < 4; ++t)
#pragma unroll
        for (int j = 0; j < 4; ++j) {
          const float p = exp2f(fmaf(sc[t][j], CE, -mrc));
          sc[t][j] = p;
          rsum += p;
        }
      rsum += __shfl_xor(rsum, 16);
      rsum += __shfl_xor(rsum, 32);
      lr += rsum;
      s16x4 pb[4];
#pragma unroll
      for (int t = 0; t < 4; ++t) {
        const u32 lo = cvtpk_bf16(sc[t][0], sc[t][1]);
        const u32 hi = cvtpk_bf16(sc[t][2], sc[t][3]);
        pb[t] = __builtin_bit_cast(s16x4, u32x2{lo, hi});
      }
      __builtin_amdgcn_s_setprio(1);
#pragma unroll
      for (int n = 0; n < 4; ++n) {
        const int row = n * 16 + l15;
        const int sw = (row & 7) << 4;
#pragma unroll
        for (int t = 0; t < 4; ++t) {
          const s16x4 va = *(const s16x4*)(vbuf + row * 256 + ((hf * 128 + t * 32 + l4 * 8) ^ sw));
          o[n] = __builtin_amdgcn_mfma_f32_16x16x16bf16_1k(va, pb[t], o[n], 0, 0, 0);
        }
      }
      __builtin_amdgcn_s_setprio(0);
    }
    __syncthreads();  // drains prefetch vmcnt + protects buf swap
  };

  stage(0, 0);
  __syncthreads();
  for (int kv = 0; kv < S; kv += 256) {
    body(0, kv);
    body(1, kv + 128);
  }
  const float inv = lr > 0.0f ? 1.0f / lr : 0.0f;
  const size_t obase = (size_t)(b * S + q0 + l15) * Dm + h * 64;
#pragma unroll
  for (int n = 0; n < 4; ++n) {
    const u32 lo = cvtpk_bf16(o[n][0] * inv, o[n][1] * inv);
    const u32 hi = cvtpk_bf16(o[n][2] * inv, o[n][3] * inv);
    *(u32x2*)&out[obase + n * 16 + l4 * 4] = u32x2{lo, hi};
  }
}

extern "C" void kernel_launch(void* const* d_in, const int* in_sizes, int n_in,
                              void* d_out, int out_size, void* d_ws, size_t ws_size,
                              hipStream_t stream) {
  (void)in_sizes; (void)n_in; (void)out_size; (void)ws_size;
  const float* x = (const float*)d_in[0];
  const u8* mask = (const u8*)d_in[1];
  const float* Wq = (const float*)d_in[2];
  const float* Wk = (const float*)d_in[3];
  const float* Wv = (const float*)d_in[4];
  const float* Wo = (const float*)d_in[5];
  const float* bo = (const float*)d_in[6];
  const float* W1 = (const float*)d_in[7];
  const float* b1 = (const float*)d_in[8];
  const float* W2 = (const float*)d_in[9];
  const float* b2 = (const float*)d_in[10];
  const float* g1 = (const float*)d_in[11];
  const float* be1 = (const float*)d_in[12];
  const float* g2 = (const float*)d_in[13];
  const float* be2 = (const float*)d_in[14];
  float* outp = (float*)d_out;

  const int B = 2, S = 2048, D = 1024, FF = 4096;
  const int M = B * S;  // 4096
  char* w = (char*)d_ws;
  const size_t MB = 1024 * 1024;
  u16* wqkvT = (u16*)(w + 0 * MB);    // [3072,1024] bf16   [0,6)
  u16* woT = (u16*)(w + 6 * MB);      // [1024,1024]        [6,8)
  u16* w1T = (u16*)(w + 8 * MB);      // [4096,1024]        [8,16)
  u16* w2T = (u16*)(w + 16 * MB);     // [1024,4096]        [16,24)
  u16* xb  = (u16*)(w + 24 * MB);     // [4096,1024]        [24,32)
  u16* qkv = (u16*)(w + 32 * MB);     // [4096,3072]        [32,56)
  u16* vt  = (u16*)(w + 56 * MB);     // [B*H,64,S]         [56,64)
  float* x0f = (float*)(w + 64 * MB); // [4096,1024] f32    [64,80)
  float* x1f = (float*)(w + 80 * MB); //                    [80,96)
  u16* x1b = (u16*)(w + 96 * MB);     // [4096,1024] bf16   [96,104)
  u8* msum = (u8*)(w + 64 * MB);      // 2 KB, dead before x0f is written
  u16* attn_o = xb;                   // xb dead after QKV gemm
  u16* ff1 = (u16*)(w + 32 * MB);     // [4096,4096] bf16, reuses qkv+vt [32,64)
  float* y0f = x0f;

  // ALL prep (6 weight transposes + x cvt + mask summary) in ONE dispatch
  prep_all<<<dim3(18432), 256, 0, stream>>>(Wq, Wk, Wv, Wo, W1, W2, x, mask,
                                            wqkvT, woT, w1T, w2T, xb, msum);

  // fused QKV projection; V third written directly transposed into vt (EPI=3); 16 waves
  gemm_bt<3, 128, 16><<<dim3(3 * D / 128, M / 128), 1024, 0, stream>>>(xb, wqkvT, M, 3 * D, D, nullptr, nullptr, qkv, (float*)vt);

  // attention: 512 blocks x 8 waves, KVBLK=128 (R22-proven best)
  attn_k<<<dim3(512), 512, 0, stream>>>(qkv, vt, mask, msum, attn_o);

  // Wo projection + bias + residual(x) -- BM=64, 8 waves (3 blocks/CU)
  gemm_bt<2, 64, 8><<<dim3(D / 128, M / 64), 512, 0, stream>>>(attn_o, woT, M, D, D, bo, x, nullptr, x0f);
  layernorm_k<1><<<dim3(M), 256, 0, stream>>>(x0f, g1, be1, x1f, x1b);
  // FFN1 -- 16 waves
  gemm_bt<1, 128, 16><<<dim3(FF / 128, M / 128), 1024, 0, stream>>>(x1b, w1T, M, FF, D, b1, nullptr, ff1, nullptr);
  gemm_bt<2, 64, 8><<<dim3(D / 128, M / 64), 512, 0, stream>>>(ff1, w2T, M, D, FF, b2, x1f, nullptr, y0f);
  layernorm_k<0><<<dim3(M), 256, 0, stream>>>(y0f, g2, be2, outp, nullptr);
}